// Round 9
// baseline (56.864 us; speedup 1.0000x reference)
//
#include <hip/hip_runtime.h>
#include <math.h>

typedef __bf16 bf16x8 __attribute__((ext_vector_type(8)));
typedef float f32x4 __attribute__((ext_vector_type(4)));

#define B_SZ 512
#define IN_F 342
#define HID  512
#define OUT_F 311
#define KA0  384    // IN_F padded
#define N2S  320    // padded layer-2 logical width
#define N2   1280   // 4*N2S

// ---------------------------------------------------------------------------
// setup (625 blocks):
//  0..191   T0[h*4+c][i] = W0[c][i][h]   (2048 x 384 bf16, i>=342 -> 0)
//  192..447 T1[h*4+c][k] = W1[c][k][h]   (2048 x 512 bf16)
//  448..607 T2[n*4+c][k] = W2[c][k][n]   (1280 x 512 bf16, n>=311 -> 0)
//  608..623 A0[m][i] = bf16(x[m][i])     (512 x 384, i>=342 -> 0)
//  624      coef[b][4]
// Interleaved rows (h*4+c) put all 4 c-slices of an h in one MFMA lane-quad,
// so the coefficient reduction is 2 shfl_xor in the GEMM epilogue.
// ---------------------------------------------------------------------------
__global__ __launch_bounds__(256) void setup_kernel(
    const float* __restrict__ p, const float* __restrict__ x,
    const float* __restrict__ W0, const float* __restrict__ W1,
    const float* __restrict__ W2, float* __restrict__ coef,
    __bf16* __restrict__ A0, __bf16* __restrict__ T0,
    __bf16* __restrict__ T1, __bf16* __restrict__ T2) {
  int bid = blockIdx.x, tid = threadIdx.x;
  if (bid >= 608) {
    if (bid == 624) {
      for (int b = tid; b < B_SZ; b += 256) {
        float p4 = p[b] * 4.0f;
        float mu = p4 - floorf(p4);
        int i1 = ((int)p4) & 3;
        float mu2 = mu * mu, mu3 = mu2 * mu;
        float c0 = -0.5f * mu3 + mu2 - 0.5f * mu;
        float c1 =  1.5f * mu3 - 2.5f * mu2 + 1.0f;
        float c2 = -1.5f * mu3 + 2.0f * mu2 + 0.5f * mu;
        float c3 =  0.5f * mu3 - 0.5f * mu2;
        float arr[4];
        arr[(i1 + 3) & 3] = c0;
        arr[i1]           = c1;
        arr[(i1 + 1) & 3] = c2;
        arr[(i1 + 2) & 3] = c3;
        coef[b * 4 + 0] = arr[0];
        coef[b * 4 + 1] = arr[1];
        coef[b * 4 + 2] = arr[2];
        coef[b * 4 + 3] = arr[3];
      }
    } else {
      int base = (bid - 608) * 32;
      for (int e = tid; e < 32 * KA0; e += 256) {
        int m = base + e / KA0, i = e % KA0;
        A0[(size_t)m * KA0 + i] =
            (i < IN_F) ? (__bf16)x[(size_t)m * IN_F + i] : (__bf16)0.0f;
      }
    }
    return;
  }
  // ---- weight transpose tiles (64 rows x 64 k), coalesced reads ----
  const float* W; __bf16* T; int t, job, Kp;
  if (bid < 192)      { job = 0; W = W0; T = T0; t = bid;       Kp = KA0; }
  else if (bid < 448) { job = 1; W = W1; T = T1; t = bid - 192; Kp = 512; }
  else                { job = 2; W = W2; T = T2; t = bid - 448; Kp = 512; }
  int R  = (job == 0) ? t / 6 : t / 8;
  int Kb = (job == 0) ? t % 6 : t % 8;
  int r0 = R * 64, k0 = Kb * 64;

  __shared__ __bf16 tile[64][66];
  int rl = tid & 63;
#pragma unroll
  for (int jj = 0; jj < 16; ++jj) {
    int kl = (tid >> 6) + jj * 4;
    int k = k0 + kl;
    float v = 0.0f;
    if (job == 0) {
      int c = r0 >> 9, h = (r0 & 511) + rl;
      if (k < IN_F) v = W[((size_t)c * IN_F + k) * 512 + h];
    } else if (job == 1) {
      int c = r0 >> 9, h = (r0 & 511) + rl;
      v = W[((size_t)c * HID + k) * 512 + h];
    } else {
      int c = r0 / N2S, n = r0 - c * N2S + rl;
      if (n < OUT_F) v = W[((size_t)c * HID + k) * OUT_F + n];
    }
    tile[rl][kl] = (__bf16)v;
  }
  __syncthreads();
  int row = tid >> 2, o0 = (tid & 3) * 16;
  bf16x8 v0 = *(const bf16x8*)&tile[row][o0];
  bf16x8 v1 = *(const bf16x8*)&tile[row][o0 + 8];
  int g;   // interleaved destination row
  if (job == 2) {
    int c = r0 / N2S, n = r0 - c * N2S + row;
    g = n * 4 + c;
  } else {
    int c = r0 >> 9, h = (r0 & 511) + row;
    g = h * 4 + c;
  }
  __bf16* dst = T + (size_t)g * Kp + k0 + o0;
  *(bf16x8*)dst = v0;
  *(bf16x8*)(dst + 8) = v1;
}

// ---------------------------------------------------------------------------
// gemm_fused<KA,OUTM>: P[m][n'] = A(M x KA bf16) @ BT(n' x KA bf16, k-major),
// n' = h*4+c interleaved. Epilogue in-register: v = cf[m][c]*(P + bias[c][h]),
// quad butterfly (shfl_xor 1,2) sums over c; OUTM=0: ELU -> bf16 E[m][h];
// OUTM=1: fp32 out[m][n] (n<311, no ELU).
// A-stripe resident in LDS; B double-buffered, statically-named regs.
// ---------------------------------------------------------------------------
template <int KA, int OUTM>
__global__ __launch_bounds__(256) void gemm_fused(
    const __bf16* __restrict__ A, const __bf16* __restrict__ BT,
    const float* __restrict__ bias, const float* __restrict__ coef,
    void* __restrict__ outv) {
  constexpr int T = KA / 64;
  constexpr int LDA = KA + 8;
  constexpr int LDT = 72;
  __shared__ __bf16 Als[64 * LDA];
  __shared__ __bf16 Bls[64 * LDT];

  const int tid = threadIdx.x;
  const int l = tid & 63;
  const int wave = tid >> 6;
  const int wm = wave >> 1, wn = wave & 1;
  const int lr = l & 15, lk = l >> 4;
  const int m0 = blockIdx.y * 64;
  const int n0 = blockIdx.x * 64;

  const int ar = tid >> 2;        // B staging row (n')
  const int ao = (tid & 3) * 2;   // first octet (k)
  const __bf16* Bp = BT + (size_t)(n0 + ar) * KA + ao * 8;

  bf16x8 b0_, b1_;   // phase 0
  bf16x8 b2_, b3_;   // phase 1
  f32x4 acc[2][2] = {};

  auto load0 = [&](int t) {
    b0_ = *(const bf16x8*)&Bp[t * 64];
    b1_ = *(const bf16x8*)&Bp[t * 64 + 8];
  };
  auto load1 = [&](int t) {
    b2_ = *(const bf16x8*)&Bp[t * 64];
    b3_ = *(const bf16x8*)&Bp[t * 64 + 8];
  };
  auto store0 = [&]() {
    *(bf16x8*)&Bls[ar * LDT + ao * 8] = b0_;
    *(bf16x8*)&Bls[ar * LDT + ao * 8 + 8] = b1_;
  };
  auto store1 = [&]() {
    *(bf16x8*)&Bls[ar * LDT + ao * 8] = b2_;
    *(bf16x8*)&Bls[ar * LDT + ao * 8 + 8] = b3_;
  };
  auto compute = [&](int t) {
#pragma unroll
    for (int kk = 0; kk < 64; kk += 32) {
      bf16x8 af[2], bg[2];
#pragma unroll
      for (int i = 0; i < 2; ++i) {
        af[i] = *(const bf16x8*)&Als[(wm * 32 + i * 16 + lr) * LDA + t * 64 + kk + lk * 8];
        bg[i] = *(const bf16x8*)&Bls[(wn * 32 + i * 16 + lr) * LDT + kk + lk * 8];
      }
#pragma unroll
      for (int i = 0; i < 2; ++i)
#pragma unroll
        for (int j = 0; j < 2; ++j)
          acc[i][j] = __builtin_amdgcn_mfma_f32_16x16x32_bf16(af[i], bg[j],
                                                              acc[i][j], 0, 0, 0);
    }
  };

  load0(0);   // B loads in flight while A-prologue runs
  load1(1);

  // ---- A-stripe -> LDS, once ----
  const int lane = tid & 63;
  for (int r = wave; r < 64; r += 4) {
    if (lane < KA / 8) {
      bf16x8 v = *(const bf16x8*)&A[(size_t)(m0 + r) * KA + lane * 8];
      *(bf16x8*)&Als[r * LDA + lane * 8] = v;
    }
  }

  for (int t = 0; t < T; t += 2) {
    __syncthreads();            // A ready (t=0) / prev compute done
    store0();
    __syncthreads();
    if (t + 2 < T) load0(t + 2);
    compute(t);
    __syncthreads();
    store1();
    __syncthreads();
    if (t + 3 < T) load1(t + 3);
    compute(t + 1);
  }

  // ---- fused epilogue: quad-reduce over c, write E/out directly ----
  const int cl = l & 3;
#pragma unroll
  for (int i = 0; i < 2; ++i) {
#pragma unroll
    for (int j = 0; j < 2; ++j) {
      int gnp = n0 + wn * 32 + j * 16 + lr;
      int hn = gnp >> 2;                       // h (OUTM=0) or n (OUTM=1)
      float bv;
      if (OUTM) bv = (hn < OUT_F) ? bias[cl * OUT_F + hn] : 0.0f;
      else      bv = bias[cl * HID + hn];
#pragma unroll
      for (int r = 0; r < 4; ++r) {
        int gm = m0 + wm * 32 + i * 16 + lk * 4 + r;
        float cf = coef[gm * 4 + cl];
        float v = cf * (acc[i][j][r] + bv);
        v += __shfl_xor(v, 1);
        v += __shfl_xor(v, 2);                 // quad now holds sum over c
        if (OUTM) {
          if (cl == 0 && hn < OUT_F)
            ((float*)outv)[(size_t)gm * OUT_F + hn] = v;
        } else {
          if (cl == 0) {
            float e = (v > 0.0f) ? v : expm1f(v);
            ((__bf16*)outv)[(size_t)gm * HID + hn] = (__bf16)e;
          }
        }
      }
    }
  }
}

extern "C" void kernel_launch(void* const* d_in, const int* in_sizes, int n_in,
                              void* d_out, int out_size, void* d_ws, size_t ws_size,
                              hipStream_t stream) {
  const float* p  = (const float*)d_in[0];
  const float* x  = (const float*)d_in[1];
  const float* W0 = (const float*)d_in[2];
  const float* b0 = (const float*)d_in[3];
  const float* W1 = (const float*)d_in[4];
  const float* b1 = (const float*)d_in[5];
  const float* W2 = (const float*)d_in[6];
  const float* b2 = (const float*)d_in[7];
  float* out = (float*)d_out;

  char* w = (char*)d_ws;
  float*  coef = (float*)w;   w += 8192;
  __bf16* A0   = (__bf16*)w;  w += (size_t)B_SZ * KA0 * 2;    // 384 KB
  __bf16* T0   = (__bf16*)w;  w += (size_t)2048 * KA0 * 2;    // 1.5 MB
  __bf16* T1   = (__bf16*)w;  w += (size_t)2048 * 512 * 2;    // 2 MB
  __bf16* T2   = (__bf16*)w;  w += (size_t)N2 * 512 * 2;      // 1.25 MB
  __bf16* E1   = (__bf16*)w;  w += (size_t)B_SZ * HID * 2;    // 512 KB
  __bf16* E2   = (__bf16*)w;  w += (size_t)B_SZ * HID * 2;    // 512 KB

  setup_kernel<<<625, 256, 0, stream>>>(p, x, W0, W1, W2, coef, A0, T0, T1, T2);

  gemm_fused<KA0, 0><<<dim3(32, 8), 256, 0, stream>>>(A0, T0, b0, coef, E1);
  gemm_fused<512, 0><<<dim3(32, 8), 256, 0, stream>>>(E1, T1, b1, coef, E2);
  gemm_fused<512, 1><<<dim3(20, 8), 256, 0, stream>>>(E2, T2, b2, coef, out);
}